// Round 8
// baseline (362.536 us; speedup 1.0000x reference)
//
#include <hip/hip_runtime.h>
#include <math.h>

// ---- problem constants ----
constexpr int B  = 32;
constexpr int N  = 196;
constexpr int D  = 768;
constexpr int E  = 200;
constexpr int TK = 20;

constexpr int NGRP = 4;        // expert groups (5 experts each)
constexpr int PRB  = 14336;    // period buffer bytes: 224 cols x 64 B (64 k fp8)
constexpr int EXB  = 114688;   // per expert: 2 matrices x 4 periods x PRB
constexpr int LK   = 40;       // k_outproj LDS stride

typedef __bf16 bf16x8 __attribute__((ext_vector_type(8)));
typedef __bf16 bf16x4 __attribute__((ext_vector_type(4)));
typedef float  f32x4  __attribute__((ext_vector_type(4)));
typedef long   longx2 __attribute__((ext_vector_type(2)));
typedef unsigned char uchar;

#define GLDS16(gp, lp)                                                        \
  __builtin_amdgcn_global_load_lds(                                           \
      (const __attribute__((address_space(1))) void*)(gp),                    \
      (__attribute__((address_space(3))) void*)(lp), 16, 0, 0)

// s_waitcnt immediates (gfx9: vm[3:0] | exp[6:4] | lgkm[11:8] | vm[5:4]@[15:14])
#define WAITVM12  __builtin_amdgcn_s_waitcnt(0x0F7C)
#define WAITVM8   __builtin_amdgcn_s_waitcnt(0x0F78)
#define WAITVM0   __builtin_amdgcn_s_waitcnt(0x0F70)
#define WAITLGKM0 __builtin_amdgcn_s_waitcnt(0xC07F)
#define BAR       __builtin_amdgcn_s_barrier()

// keep a 64-bit value live so the compiler cannot narrow a b128 LDS read
#define KEEP64(v) asm volatile("" : : "v"(v))

__device__ __forceinline__ float gelu_fast(float x) {
  float u = x * fmaf(x * x, 0.044715f, 1.0f);
  float e = exp2f(-2.3022084f * u);
  return x * __builtin_amdgcn_rcpf(1.0f + e);
}

__device__ __forceinline__ uchar f32_to_f8(float v) {
  return (uchar)(__builtin_amdgcn_cvt_pk_fp8_f32(v, v, 0, false) & 0xff);
}

// ---------------------------------------------------------------------------
// Kernel 1 (fused prep), 1792 blocks, all branches <= ~29.6KB LDS (5/CU):
//   blocks    0..31   : router (computes own token-mean from x)
//   blocks   32..831  : W1,W2 -> fp8 period format, half-col blocks
//   blocks  832..1215 : LN -> z fp8 staging layout
//   blocks 1216..1791 : Wo -> bf16
// z layout: zb[b][pair 0..3][d 0..767][64B], 64B = [q_phys][even 8B|odd 8B],
// q_phys = ((tok>>3)&3) ^ ((d>>1)&3).  Tokens 196..255 zero.
// W chunk swizzle: physical chunk qp holds logical chunk qp ^ ((col>>1)&3).
// ---------------------------------------------------------------------------
__global__ __launch_bounds__(256) void k_prep(
    const float* __restrict__ x,
    const float* __restrict__ W1, const float* __restrict__ W2,
    const float* __restrict__ Wo, const float* __restrict__ Wr,
    uchar* __restrict__ zb, uchar* __restrict__ Wf, __bf16* __restrict__ Wob,
    float* __restrict__ probs, int* __restrict__ idxg,
    float* __restrict__ wg) {
  int bx = blockIdx.x;
  int t = threadIdx.x;
  __shared__ alignas(16) uchar ls[28672];
  __shared__ float sp[E];
  __shared__ float smax, ssum;
  __shared__ float svals[TK];
  __shared__ int   sidx[TK];

  if (bx < 32) {
    // ---- router (own token-mean from x) ----
    int b = bx;
    int lane = t & 63, wave = t >> 6;
    float* smu = (float*)ls;
    {
      const float* xb = x + (size_t)b * N * D;
      float a0 = 0.f, a1 = 0.f, a2 = 0.f;
      #pragma unroll 4
      for (int n = 0; n < 196; ++n) {
        const float* rp = xb + (size_t)n * D + t;
        a0 += rp[0]; a1 += rp[256]; a2 += rp[512];
      }
      const float inv = 1.0f / (float)N;
      smu[t] = a0 * inv; smu[t + 256] = a1 * inv; smu[t + 512] = a2 * inv;
    }
    __syncthreads();
    const float4* m4 = (const float4*)smu;
    #pragma unroll 1
    for (int i = 0; i < 50; ++i) {
      int e = wave * 50 + i;
      const float4* wr4 = (const float4*)(Wr + (size_t)e * D);
      float acc = 0.f;
      #pragma unroll
      for (int j = 0; j < 3; ++j) {
        float4 w = wr4[lane + j * 64], mm = m4[lane + j * 64];
        acc = fmaf(w.x, mm.x, acc); acc = fmaf(w.y, mm.y, acc);
        acc = fmaf(w.z, mm.z, acc); acc = fmaf(w.w, mm.w, acc);
      }
      #pragma unroll
      for (int off = 32; off > 0; off >>= 1) acc += __shfl_down(acc, off);
      if (lane == 0) sp[e] = acc;
    }
    __syncthreads();
    if (t < 64) {
      float mx = -1e30f;
      for (int e = t; e < E; e += 64) mx = fmaxf(mx, sp[e]);
      #pragma unroll
      for (int off = 32; off > 0; off >>= 1) mx = fmaxf(mx, __shfl_down(mx, off));
      if (t == 0) smax = mx;
    }
    __syncthreads();
    if (t < E) sp[t] = exp2f((sp[t] - smax) * 1.44269504f);
    __syncthreads();
    if (t < 64) {
      float s = 0.f;
      for (int e = t; e < E; e += 64) s += sp[e];
      #pragma unroll
      for (int off = 32; off > 0; off >>= 1) s += __shfl_down(s, off);
      if (t == 0) ssum = s;
    }
    __syncthreads();
    if (t < E) {
      sp[t] = sp[t] / ssum;
      probs[(size_t)b * E + t] = sp[t];
    }
    __syncthreads();
    for (int k = 0; k < TK; ++k) {
      if (t < 64) {
        float bv = -1e30f; int bi = 0;
        for (int e = t; e < E; e += 64) {
          float v = sp[e];
          if (v > bv) { bv = v; bi = e; }
        }
        #pragma unroll
        for (int off = 32; off > 0; off >>= 1) {
          float ov = __shfl_down(bv, off);
          int   oi = __shfl_down(bi, off);
          if (ov > bv || (ov == bv && oi < bi)) { bv = ov; bi = oi; }
        }
        if (t == 0) {
          svals[k] = bv; sidx[k] = bi;
          sp[bi] = -2e30f;
        }
      }
      __syncthreads();
    }
    if (t == 0) {
      float s = 0.f;
      for (int k = 0; k < TK; ++k) s += svals[k];
      float inv = 1.0f / s;
      for (int k = 0; k < TK; ++k) {
        wg[b * TK + k]   = svals[k] * inv;
        idxg[b * TK + k] = sidx[k];
      }
    }
    return;
  }

  if (bx < 832) {
    // ---- W1/W2 convert, half-block: cols [r0, r0+112) ----
    int bc = bx - 32;
    int e = bc >> 2, mat = (bc >> 1) & 1, half = bc & 1;
    int r0 = half * 112;
    int nrows = half ? 84 : 112;        // real rows in this half (196 total)
    for (int i = t; i < 1792; i += 256) ((uint4*)ls)[i] = (uint4){0, 0, 0, 0};
    __syncthreads();
    const float* src = (mat ? W2 : W1) + (size_t)e * 196 * 196;
    for (int i = t; i < nrows * 49; i += 256) {
      int rl = i / 49, c4 = (i - rl * 49) * 4;
      float4 v = *(const float4*)&src[(size_t)(r0 + rl) * 196 + c4];
      int lo = __builtin_amdgcn_cvt_pk_fp8_f32(v.x, v.y, 0, false);
      unsigned int pk = (unsigned int)__builtin_amdgcn_cvt_pk_fp8_f32(v.z, v.w, lo, true);
      *(unsigned int*)&ls[rl * 256 + c4] = pk;
    }
    __syncthreads();
    uchar* dst = Wf + (size_t)e * EXB + mat * 4 * PRB;
    for (int s = t; s < 1792; s += 256) {
      int p = s / 448, rem = s - p * 448;
      int cl = rem >> 2, qp = rem & 3;
      int col = r0 + cl;
      int ql = qp ^ ((col >> 1) & 3);
      unsigned long lo = *(const unsigned long*)&ls[cl * 256 + p * 64 + ql * 8];
      unsigned long hi = *(const unsigned long*)&ls[cl * 256 + p * 64 + 32 + ql * 8];
      longx2 o; o[0] = (long)lo; o[1] = (long)hi;
      *(longx2*)&dst[(size_t)(p * 896 + col * 4 + qp) * 16] = o;
    }
    return;
  }

  if (bx < 1216) {
    // ---- LN -> z fp8 ----
    int bl = bx - 832;
    int b = bl / 12, dt = bl % 12;
    int d0 = dt * 64;
    int q = t >> 6, d = t & 63;
    uchar* zt = ls;                       // 16384
    float* ps = (float*)(ls + 16384);     // 1024
    float* pq = (float*)(ls + 17408);     // 1024
    float* ms = (float*)(ls + 18432);     // 256
    float* rss = (float*)(ls + 18688);    // 256

    for (int i = t; i < 1024; i += 256) ((uint4*)zt)[i] = (uint4){0, 0, 0, 0};

    const float* xp = x + ((size_t)b * N + q * 49) * D + d0 + d;
    float v[49];
    float s = 0.f, sq = 0.f;
    #pragma unroll
    for (int n = 0; n < 49; ++n) {
      v[n] = xp[(size_t)n * D];
      s += v[n]; sq += v[n] * v[n];
    }
    ps[t] = s; pq[t] = sq;
    __syncthreads();
    if (t < 64) {
      float S = ps[t] + ps[t + 64] + ps[t + 128] + ps[t + 192];
      float Q = pq[t] + pq[t + 64] + pq[t + 128] + pq[t + 192];
      float m = S * (1.0f / N);
      float var = Q * (1.0f / N) - m * m;
      ms[t] = m; rss[t] = rsqrtf(var + 1e-5f);
    }
    __syncthreads();
    float m = ms[d], r = rss[d];
    int dsw = (d >> 1) & 3;
    #pragma unroll
    for (int n = 0; n < 49; ++n) {
      int tok = q * 49 + n;
      int qp = ((tok >> 3) & 3) ^ dsw;
      int off = d * 256 + (tok >> 6) * 64 + qp * 16 + ((tok >> 5) & 1) * 8 + (tok & 7);
      zt[off] = f32_to_f8((v[n] - m) * r);
    }
    __syncthreads();
    #pragma unroll
    for (int pair = 0; pair < 4; ++pair) {
      uint4* dst = (uint4*)(zb + (((size_t)b * 4 + pair) * 768 + d0) * 64);
      dst[t] = ((const uint4*)zt)[(t >> 2) * 16 + pair * 4 + (t & 3)];
    }
    return;
  }

  // ---- Wo -> bf16 ----
  int i = (bx - 1216) * 256 + t;
  float4 v = *(const float4*)&Wo[(size_t)i * 4];
  bf16x4 o = {(__bf16)v.x, (__bf16)v.y, (__bf16)v.z, (__bf16)v.w};
  *(bf16x4*)&Wob[(size_t)i * 4] = o;
}

// ---------------------------------------------------------------------------
// Kernel 5: fused expert MLP, fp8 MFMA.
// 256 thr (4 waves, 2x2 tiling), 64-row d-tile, 2 blocks/CU (79.7KB LDS).
// 4-deep prefetch ring (buffer 3 aliases zs, dead after zf hoist) ->
// ONE barrier per period.  GEMM1 swapped operands: C[h][d].
// Period 3 of both GEMMs runs HALF-K (odd 8B = k 224..255 all-zero).
// Wave-pair 1 (wcol=112) skips ct=6 in both GEMMs: h/n 208..223 are dead.
// ---------------------------------------------------------------------------
__global__ __launch_bounds__(256, 2) void k_expert(
    const uchar* __restrict__ zb, const uchar* __restrict__ Wf,
    const float* __restrict__ b1, const float* __restrict__ b2,
    const int* __restrict__ idxg, const float* __restrict__ wg,
    __bf16* __restrict__ mixg) {
  __shared__ alignas(16) uchar pool[75776];
  __shared__ alignas(16) __bf16 b1s[5 * 196];
  __shared__ float bsum_s[196];
  __shared__ int   eidx_s[5];
  __shared__ float w_s[5];
  uchar* zs  = pool;                 // 16384: [pair][row 0..63][64B]; ring buf 3 after hoist
  uchar* at  = pool + 16384;         // 16384: same layout (k = h)
  uchar* wsb = pool + 32768;         // 43008: ring buffers 0..2 x 14336
  __bf16* tb = (__bf16*)pool;        // final transpose scratch (after last BAR)

  int xw = blockIdx.x & 7, rr_ = blockIdx.x >> 3;
  int j = rr_ / 12, dt = rr_ - j * 12;
  int gid = j * 8 + xw;
  int g = gid & 3, b = gid >> 2;
  int d0 = dt * 64;

  int t = threadIdx.x;
  int lane = t & 63, wave = t >> 6;
  int quad = lane >> 4, l16 = lane & 15;
  int wrow = (wave & 1) * 32;        // d rows: 0 / 32
  int wcol = (wave >> 1) * 112;      // h cols: 0 / 112
  bool w0 = (wcol == 0);             // wave-pair 0 owns the full 7 ct tiles
  int qp = quad ^ ((l16 >> 1) & 3);  // phase-balanced XOR swizzle

  // ---- prologue ----
  if (t < 5) {
    eidx_s[t] = idxg[b * TK + g * 5 + t];
    w_s[t]    = wg[b * TK + g * 5 + t];
  }
  for (int i = t; i < 980; i += 256) {
    int kk = i / 196, col = i - kk * 196;
    int ee = idxg[b * TK + g * 5 + kk];
    b1s[i] = (__bf16)b1[ee * 196 + col];
  }
  if (t < 196) {
    float s = 0.f;
    #pragma unroll
    for (int k5 = 0; k5 < 5; ++k5) {
      int ee = idxg[b * TK + g * 5 + k5];
      s += wg[b * TK + g * 5 + k5] * b2[ee * 196 + t];
    }
    bsum_s[t] = s;
  }
  __syncthreads();   // drains prologue vmem

  // ---- z staging: 4 flat 4096-B pair blocks ----
  {
    const uchar* zbase = zb + ((size_t)b * 4 * 768 + d0) * 64;
    #pragma unroll
    for (int p = 0; p < 4; ++p)
      GLDS16(zbase + (size_t)p * (768 * 64) + t * 16, zs + p * 4096 + t * 16);
  }

  // ---- W ring staging offsets (896 slots; threads duplicate last 128) ----
  int s0 = t * 16, s1 = (t + 256) * 16, s2 = (t + 512) * 16;
  int s3 = ((t & 127) + 768) * 16;

  auto issue = [&](int qn) {
    int qq = qn > 39 ? 39 : qn;
    int kk2 = qq >> 3, rem = qq & 7;
    const uchar* src = Wf + (size_t)eidx_s[kk2] * EXB + rem * PRB;
    int bi = qn & 3;
    uchar* lb = (bi == 3) ? pool : wsb + bi * PRB;
    GLDS16(src + s0, lb + s0);
    GLDS16(src + s1, lb + s1);
    GLDS16(src + s2, lb + s2);
    GLDS16(src + s3, lb + s3);
  };
  issue(0); issue(1); issue(2);

  // ---- hoist z frags (shared across all 5 experts; B-operand of GEMM1) ----
  WAITVM12;  // z staging (oldest 4 vmem) done; ring still in flight
  BAR;
  const uchar* zbase_l = zs + (wrow + l16) * 64 + qp * 16;
  longx2 zf[3][2];
  #pragma unroll
  for (int p = 0; p < 3; ++p) {
    zf[p][0] = *(const longx2*)(zbase_l + p * 4096);
    zf[p][1] = *(const longx2*)(zbase_l + p * 4096 + 1024);
  }
  long z3r0, z3r1;
  {
    longx2 zt0 = *(const longx2*)(zbase_l + 3 * 4096);
    longx2 zt1 = *(const longx2*)(zbase_l + 3 * 4096 + 1024);
    KEEP64(zt0[1]); KEEP64(zt1[1]);
    z3r0 = zt0[0]; z3r1 = zt1[0];
  }

  const uchar* abase = at + (wrow + l16) * 64 + qp * 16;

  f32x4 macc[14];
  #pragma unroll
  for (int i = 0; i < 14; ++i) macc[i] = (f32x4){0.f, 0.f, 0.f, 0.f};

  #pragma unroll 1
  for (int kk = 0; kk < 5; ++kk) {
    float wkv = w_s[kk];
    f32x4 hacc[14];
    #pragma unroll
    for (int i = 0; i < 14; ++i) hacc[i] = (f32x4){0.f, 0.f, 0.f, 0.f};

    // ---- GEMM1: 3 full periods + 1 half-K period.  C[h][d] ----
    #pragma unroll 1
    for (int p = 0; p < 3; ++p) {
      int q = kk * 8 + p;
      WAITVM8;
      BAR;
      int bi = q & 3;
      const uchar* buf = (bi == 3) ? pool : wsb + bi * PRB;
      const uchar* bb = buf + (wcol + l16) * 64 + qp * 16;
      __builtin_amdgcn_s_setprio(1);
      #pragma unroll
      for (int ct = 0; ct < 7; ++ct) {
        if (ct < 6 || w0) {
          longx2 bf = *(const longx2*)(bb + ct * 1024);
          hacc[ct]     = __builtin_amdgcn_mfma_f32_16x16x32_fp8_fp8(bf[0], zf[p][0][0], hacc[ct], 0, 0, 0);
          hacc[ct]     = __builtin_amdgcn_mfma_f32_16x16x32_fp8_fp8(bf[1], zf[p][0][1], hacc[ct], 0, 0, 0);
          hacc[7 + ct] = __builtin_amdgcn_mfma_f32_16x16x32_fp8_fp8(bf[0], zf[p][1][0], hacc[7 + ct], 0, 0, 0);
          hacc[7 + ct] = __builtin_amdgcn_mfma_f32_16x16x32_fp8_fp8(bf[1], zf[p][1][1], hacc[7 + ct], 0, 0, 0);
        }
      }
      __builtin_amdgcn_s_setprio(0);
      issue(q + 3);
    }
    {
      int q = kk * 8 + 3;           // half-K: tokens 192..223 only
      WAITVM8;
      BAR;
      int bi = q & 3;
      const uchar* buf = (bi == 3) ? pool : wsb + bi * PRB;
      const uchar* bb = buf + (wcol + l16) * 64 + qp * 16;
      __builtin_amdgcn_s_setprio(1);
      #pragma unroll
      for (int ct = 0; ct < 7; ++ct) {
        if (ct < 6 || w0) {
          longx2 bf = *(const longx2*)(bb + ct * 1024);
          KEEP64(bf[1]);              // force b128 read (bank-friendly)
          hacc[ct]     = __builtin_amdgcn_mfma_f32_16x16x32_fp8_fp8(bf[0], z3r0, hacc[ct], 0, 0, 0);
          hacc[7 + ct] = __builtin_amdgcn_mfma_f32_16x16x32_fp8_fp8(bf[0], z3r1, hacc[7 + ct], 0, 0, 0);
        }
      }
      __builtin_amdgcn_s_setprio(0);
      issue(q + 3);
    }

    // ---- epilogue: a = gelu(h+b1)*w_k -> at, packed 4 h per b32 store ----
    // lane holds h = wcol + ct*16 + quad*4 + (0..3) at d = wrow + rt*16 + l16.
    // at byte addr: (h>>6)*4096 + d*64 + ((((h>>3)&3) ^ ((d>>1)&3))<<4)
    //             + ((h>>5)&1)*8 + (h&7)   -- matches GEMM2's reads.
    // invalid hb (196..220) stores 0, zeroing pair-3 even-half tail each kk.
    #pragma unroll
    for (int ct = 0; ct < 7; ++ct) {
      int hb = wcol + ct * 16 + quad * 4;
      bool valid = hb < 196;
      unsigned pk0 = 0u, pk1 = 0u;
      if (valid) {
        bf16x4 b4 = *(const bf16x4*)&b1s[kk * 196 + hb];
        float bv0 = (float)b4[0], bv1 = (float)b4[1];
        float bv2 = (float)b4[2], bv3 = (float)b4[3];
        f32x4 h0 = hacc[ct], h1 = hacc[7 + ct];
        pk0 = (unsigned)__builtin_amdgcn_cvt_pk_fp8_f32(
                  gelu_fast(h0[0] + bv0) * wkv, gelu_fast(h0[1] + bv1) * wkv, 0, false);
        pk0 = (unsigned)__builtin_amdgcn_cvt_pk_fp8_f32(
                  gelu_fast(h0[2] + bv2) * wkv, gelu_fast(h0[3] + bv3) * wkv, (int)pk0, true);
        pk1 = (unsigned)__builtin_amdgcn_cvt_pk_fp8_f32(
                  gelu_fast(h1[0] + bv0) * wkv, gelu_fast(h1[1] + bv1) * wkv, 0, false);
        pk1 = (unsigned)__builtin_amdgcn_cvt_pk_fp8_f32(
                  gelu_fast(h1[2] + bv2) * wkv, gelu_fast(h1[3] + bv3) * wkv, (int)pk1, true);
      }
      int d0r = wrow + l16;
      int addr0 = (hb >> 6) * 4096 + d0r * 64 + ((((hb >> 3) & 3) ^ ((d0r >> 1) & 3)) << 4)
                + ((hb >> 5) & 1) * 8 + (quad & 1) * 4;
      *(unsigned*)&at[addr0]        = pk0;   // rt = 0: d = wrow + l16
      *(unsigned*)&at[addr0 + 1024] = pk1;   // rt = 1: d+16, same chunk-xor
    }
    WAITLGKM0;   // own at-writes drained before the next barrier

    // ---- GEMM2: 3 full periods + 1 half-K period (C[d][n]) ----
    #pragma unroll 1
    for (int p = 0; p < 3; ++p) {
      int q = kk * 8 + 4 + p;
      WAITVM8;
      BAR;
      int bi = q & 3;
      const uchar* buf = (bi == 3) ? pool : wsb + bi * PRB;
      const uchar* bb = buf + (wcol + l16) * 64 + qp * 16;
      longx2 a0 = *(const longx2*)(abase + p * 4096);
      longx2 a1 = *(const longx2*)(abase + p * 4096 + 1024);
      __builtin_amdgcn_s_setprio(1);
      #pragma unroll
      for (int ct = 0; ct < 7; ++ct) {
        if (ct < 6 || w0) {
          longx2 bf = *(const longx2*)(bb + ct * 1024);
          macc[ct]     = __builtin_amdgcn_mfma_f32_16x16x32_fp8_fp8(a0[0], bf[0], macc[ct], 0, 0, 0);
          macc[ct]     = __builtin_amdgcn_mfma_f32_16x16x32_fp8_fp8(a0[1], bf[1], macc[ct], 0, 0, 0);
          macc[7 + ct] = __builtin_amdgcn_mfma_f32_16x16x32_fp8_fp8(a1[0], bf[0], macc[7 + ct], 0, 0, 0);
          macc[7 + ct] = __builtin_amdgcn_mfma_f32_16x16x32_fp8_fp8(a1[1], bf[1], macc[7 + ct], 0, 0, 0);
        }
      }
      __builtin_amdgcn_s_setprio(0);
      issue(q + 3);
    }
    {
      int q = kk * 8 + 7;           // half-K: h 192..223 only
      WAITVM8;
      BAR;
      int bi = q & 3;
      const uchar* buf = (bi == 3) ? pool : wsb + bi * PRB;
      const uchar* bb = buf + (wcol + l16) * 64 + qp * 16;
      long a0h, a1h;
      {
        longx2 at0 = *(const longx2*)(abase + 3 * 4096);
        longx2 at1 = *(const longx2*)(abase + 3 * 4096 + 1024);
        KEEP64(at0[1]); KEEP64(at1[1]);
        a0h = at0[0]; a1h = at1[0];
      }
      __builtin_amdgcn_s_setprio(1);
      #pragma unroll
      for (int ct = 0; ct < 7; ++ct) {
        if (ct < 6 || w0) {
          longx2 bf = *(const longx2*)(bb + ct * 1024);
          KEEP64(bf[1]);              // force b128 read (bank-friendly)
          macc[ct]     = __builtin_amdgcn_mfma_f32_16x16x32_fp8_fp8(a0h, bf[0], macc[ct], 0, 0, 0);
          macc[7 + ct] = __builtin_amdgcn_mfma_f32_16x16x32_fp8_fp8(a1h, bf[0], macc[7 + ct], 0, 0, 0);
        }
      }
      __builtin_amdgcn_s_setprio(0);
      issue(q + 3);
    }
  }

  // ---- drain async; add bsum = sum_k w_k*b2_k[n]; packed b64 transpose ----
  WAITVM0;
  BAR;
  #pragma unroll
  for (int ct = 0; ct < 7; ++ct) {
    int ncol = wcol + ct * 16 + l16;
    float bsum = (ncol < 196) ? bsum_s[ncol] : 0.f;
    #pragma unroll
    for (int rt = 0; rt < 2; ++rt) {
      f32x4 v = macc[rt * 7 + ct];
      bf16x4 o = {(__bf16)(v[0] + bsum), (__bf16)(v[1] + bsum),
                  (__bf16)(v[2] + bsum), (__bf16)(v[3] + bsum)};
      *(bf16x4*)&tb[ncol * 68 + wrow + rt * 16 + quad * 4] = o;
    }
  }
  __syncthreads();
  __bf16* mp = mixg + ((size_t)(g * B + b) * N) * D + d0;
  #pragma unroll
  for (int i = 0; i < 7; ++i) {
    int s = i * 256 + t;
    if (s < 1568) {
      int n = s >> 3, c = s & 7;
      const uint2* pa = (const uint2*)&tb[n * 68 + c * 8];
      uint2 v0 = pa[0], v1 = pa[1];
      uint4 v = {v0.x, v0.y, v1.x, v1.y};
      *(uint4*)&mp[(size_t)n * D + c * 8] = v;
    }
  }
}

// ---------------------------------------------------------------------------
// Kernel 6: out = (sum_g mixg_g) @ Wo^T + bo; block 0 also computes aux loss.
// 32-row m-tiles (grid 588); 4 blocks/CU -> all blocks resident.
// ---------------------------------------------------------------------------
__global__ __launch_bounds__(256, 4) void k_outproj(
    const __bf16* __restrict__ mixg, const __bf16* __restrict__ Wob,
    const float* __restrict__ bo, const float* __restrict__ probs,
    const int* __restrict__ idxg, float* __restrict__ out,
    float* __restrict__ out_aux) {
  __shared__ alignas(16) __bf16 As[32 * LK];
  __shared__ alignas(16) __bf16 Bs[256 * LK];
  const size_t GS = (size_t)B * N * D;

  int t = threadIdx.x;
  if (blockIdx.x == 0 && t < 32) {
    int top1 = idxg[t * TK];
    float s = 0.f;
    for (int bb = 0; bb < B; ++bb) s += probs[(size_t)bb * E + top1];
    #pragma unroll
    for (int off = 16; off > 0; off >>= 1) s += __shfl_down(s, off);
    if (t == 0) out_aux[0] = s * ((float)E / ((float)B * (float)B));
  }

  int m0 = (blockIdx.x % 196) * 32;
  int e0 = (blockIdx.x / 196) * 256;
  int lane = t & 63, wave = t >> 6;
  int quad = lane >> 4, l16 = lane & 15;
  int wrow = (wave & 1) * 16;
  int wcol = (wave >> 1) * 128;
  int arow = t >> 2, ach = t & 3;      // A-staging: threads 0..127 cover 32 rows
  const __bf16* ap0 = mixg + (size_t)(m0 + (arow & 31)) * D + ach * 8;

  f32x4 acc[8];
  #pragma unroll
  for (int i = 0; i < 8; ++i) acc[i] = (f32x4){0.f, 0.f, 0.f, 0.f};

  const uint4* wsrc = (const uint4*)Wob;
  #pragma unroll 1
  for (int c = 0; c < 24; ++c) {
    int k0 = c * 32;
    __syncthreads();
    if (t < 128) {
      const __bf16* ap = ap0 + k0;
      bf16x8 g0 = *(const bf16x8*)(ap);
      bf16x8 g1 = *(const bf16x8*)(ap + GS);
      bf16x8 g2 = *(const bf16x8*)(ap + 2 * GS);
      bf16x8 g3 = *(const bf16x8*)(ap + 3 * GS);
      bf16x8 r;
      #pragma unroll
      for (int jj = 0; jj < 8; ++jj)
        r[jj] = (__bf16)((float)g0[jj] + (float)g1[jj] + (float)g2[jj] + (float)g3[jj]);
      *(bf16x8*)&As[arow * LK + ach * 8] = r;
    }
    for (int p = t; p < 1024; p += 256) {
      int rr = p >> 2, sub = p & 3;
      uint4 v = wsrc[(((size_t)(e0 + rr)) * D + k0) / 8 + sub];
      *(uint4*)&Bs[rr * LK + sub * 8] = v;
    }
    __syncthreads();
    bf16x8 a0 = *(const bf16x8*)&As[(wrow + l16) * LK + quad * 8];
    #pragma unroll
    for (int ct = 0; ct < 8; ++ct) {
      bf16x8 bfr = *(const bf16x8*)&Bs[(wcol + ct * 16 + l16) * LK + quad * 8];
      acc[ct] = __builtin_amdgcn_mfma_f32_16x16x32_bf16(a0, bfr, acc[ct], 0, 0, 0);
    }
  }

  #pragma unroll
  for (int ct = 0; ct < 8; ++ct) {
    int e = e0 + wcol + ct * 16 + l16;
    float bov = bo[e];
    #pragma unroll
    for (int rx = 0; rx < 4; ++rx) {
      int m = m0 + wrow + quad * 4 + rx;
      out[(size_t)m * D + e] = acc[ct][rx] + bov;
    }
  }
}

// ---------------------------------------------------------------------------
extern "C" void kernel_launch(void* const* d_in, const int* in_sizes, int n_in,
                              void* d_out, int out_size, void* d_ws, size_t ws_size,
                              hipStream_t stream) {
  const float* x  = (const float*)d_in[0];
  const float* Wr = (const float*)d_in[1];
  const float* W1 = (const float*)d_in[2];
  const float* b1 = (const float*)d_in[3];
  const float* W2 = (const float*)d_in[4];
  const float* b2 = (const float*)d_in[5];
  const float* Wo = (const float*)d_in[6];
  const float* bo = (const float*)d_in[7];
  float* out = (float*)d_out;

  char* p = (char*)d_ws;
  auto alloc = [&](size_t bytes) {
    char* r = p;
    p += (bytes + 255) & ~(size_t)255;
    return r;
  };
  uchar*  zb   = (uchar*)alloc((size_t)B * 4 * 768 * 64);
  uchar*  Wf   = (uchar*)alloc((size_t)E * EXB);
  __bf16* Wob  = (__bf16*)alloc((size_t)D * D * 2);
  __bf16* mixg = (__bf16*)alloc((size_t)NGRP * B * N * D * 2);
  float*  probs= (float*)alloc((size_t)B * E * 4);
  int*    idxg = (int*)alloc((size_t)B * TK * 4);
  float*  wg   = (float*)alloc((size_t)B * TK * 4);

  k_prep<<<dim3(1792), dim3(256), 0, stream>>>(x, W1, W2, Wo, Wr,
                                               zb, Wf, Wob, probs, idxg, wg);
  k_expert<<<dim3(1536), dim3(256), 0, stream>>>(zb, Wf, b1, b2, idxg, wg, mixg);
  k_outproj<<<dim3(588), dim3(256), 0, stream>>>(mixg, Wob, bo, probs, idxg,
                                                 out, out + (size_t)B * N * D);
}

// Round 9
// 333.165 us; speedup vs baseline: 1.0882x; 1.0882x over previous
//
#include <hip/hip_runtime.h>
#include <math.h>

// ---- problem constants ----
constexpr int B  = 32;
constexpr int N  = 196;
constexpr int D  = 768;
constexpr int E  = 200;
constexpr int TK = 20;

constexpr int NGRP = 4;        // expert groups (5 experts each)
constexpr int PRB  = 14336;    // period buffer bytes: 224 cols x 64 B (64 k fp8)
constexpr int EXB  = 114688;   // per expert: 2 matrices x 4 periods x PRB
constexpr int LK2  = 72;       // k_outproj LDS stride (64 k + 8 pad)

typedef __bf16 bf16x8 __attribute__((ext_vector_type(8)));
typedef __bf16 bf16x4 __attribute__((ext_vector_type(4)));
typedef float  f32x4  __attribute__((ext_vector_type(4)));
typedef long   longx2 __attribute__((ext_vector_type(2)));
typedef unsigned char uchar;

#define GLDS16(gp, lp)                                                        \
  __builtin_amdgcn_global_load_lds(                                           \
      (const __attribute__((address_space(1))) void*)(gp),                    \
      (__attribute__((address_space(3))) void*)(lp), 16, 0, 0)

// s_waitcnt immediates (gfx9: vm[3:0] | exp[6:4] | lgkm[11:8] | vm[5:4]@[15:14])
#define WAITVM12  __builtin_amdgcn_s_waitcnt(0x0F7C)
#define WAITVM8   __builtin_amdgcn_s_waitcnt(0x0F78)
#define WAITVM0   __builtin_amdgcn_s_waitcnt(0x0F70)
#define WAITLGKM0 __builtin_amdgcn_s_waitcnt(0xC07F)
#define BAR       __builtin_amdgcn_s_barrier()

// keep a 64-bit value live so the compiler cannot narrow a b128 LDS read
#define KEEP64(v) asm volatile("" : : "v"(v))

__device__ __forceinline__ float gelu_fast(float x) {
  float u = x * fmaf(x * x, 0.044715f, 1.0f);
  float e = exp2f(-2.3022084f * u);
  return x * __builtin_amdgcn_rcpf(1.0f + e);
}

__device__ __forceinline__ uchar f32_to_f8(float v) {
  return (uchar)(__builtin_amdgcn_cvt_pk_fp8_f32(v, v, 0, false) & 0xff);
}

// ---------------------------------------------------------------------------
// Kernel 1: token-mean + LN over N -> z fp8 in expert-staging layout:
// zb[b][pair 0..3][d 0..767][64B], 64B = [q_phys][even-chunk 8B|odd-chunk 8B],
// q_phys = ((tok>>3)&3) ^ ((d>>1)&3).  Tokens 196..255 zero.
// ---------------------------------------------------------------------------
__global__ __launch_bounds__(256) void k_ln(const float* __restrict__ x,
                                            uchar* __restrict__ zb,
                                            float* __restrict__ mu) {
  int b = blockIdx.x / 12, dt = blockIdx.x % 12;
  int d0 = dt * 64;
  int t = threadIdx.x;
  int q = t >> 6, d = t & 63;
  __shared__ float ps[256], pq[256];
  __shared__ float ms[64], rss[64];
  __shared__ alignas(16) uchar zt[64 * 256];

  for (int i = t; i < 1024; i += 256) ((uint4*)zt)[i] = (uint4){0, 0, 0, 0};

  const float* xp = x + ((size_t)b * N + q * 49) * D + d0 + d;
  float v[49];
  float s = 0.f, sq = 0.f;
  #pragma unroll
  for (int n = 0; n < 49; ++n) {
    v[n] = xp[(size_t)n * D];
    s += v[n]; sq += v[n] * v[n];
  }
  ps[t] = s; pq[t] = sq;
  __syncthreads();
  if (t < 64) {
    float S = ps[t] + ps[t + 64] + ps[t + 128] + ps[t + 192];
    float Q = pq[t] + pq[t + 64] + pq[t + 128] + pq[t + 192];
    float m = S * (1.0f / N);
    float var = Q * (1.0f / N) - m * m;
    ms[t] = m; rss[t] = rsqrtf(var + 1e-5f);
    mu[(size_t)b * D + d0 + t] = m;
  }
  __syncthreads();
  float m = ms[d], r = rss[d];
  int dsw = (d >> 1) & 3;
  #pragma unroll
  for (int n = 0; n < 49; ++n) {
    int tok = q * 49 + n;
    int qp = ((tok >> 3) & 3) ^ dsw;
    int off = d * 256 + (tok >> 6) * 64 + qp * 16 + ((tok >> 5) & 1) * 8 + (tok & 7);
    zt[off] = f32_to_f8((v[n] - m) * r);
  }
  __syncthreads();
  #pragma unroll
  for (int pair = 0; pair < 4; ++pair) {
    uint4* dst = (uint4*)(zb + (((size_t)b * 4 + pair) * 768 + d0) * 64);
    dst[t] = ((const uint4*)zt)[(t >> 2) * 16 + pair * 4 + (t & 3)];
  }
}

// ---------------------------------------------------------------------------
// Kernel 2 (fused): blocks 0..799    : W1,W2 -> fp8 period format, HALF-cols
//                   blocks 800..1375 : Wo -> bf16
//                   blocks 1376..1407: router (coalesced wave-parallel dot)
// Convert split into 2 half-blocks of 112 cols each -> 28.7KB LDS.
// chunk swizzle: physical chunk qp holds logical chunk qp ^ ((col>>1)&3).
// ---------------------------------------------------------------------------
__global__ __launch_bounds__(256) void k_prep(
    const float* __restrict__ W1, const float* __restrict__ W2,
    const float* __restrict__ Wo,
    uchar* __restrict__ Wf, __bf16* __restrict__ Wob,
    const float* __restrict__ mu, const float* __restrict__ Wr,
    float* __restrict__ probs, int* __restrict__ idxg,
    float* __restrict__ wg) {
  int bx = blockIdx.x;
  int t = threadIdx.x;
  __shared__ alignas(16) uchar ls[112 * 256];   // convert: [row-local][k]
  __shared__ float sp[E];
  __shared__ float smax, ssum;
  __shared__ float svals[TK];
  __shared__ int   sidx[TK];

  if (bx >= 1376) {
    // ---- router ----
    int b = bx - 1376;
    int lane = t & 63, wave = t >> 6;
    float* smu = (float*)ls;
    for (int i = t; i < 768; i += 256) smu[i] = mu[(size_t)b * D + i];
    __syncthreads();
    const float4* m4 = (const float4*)smu;
    #pragma unroll 1
    for (int i = 0; i < 50; ++i) {
      int e = wave * 50 + i;
      const float4* wr4 = (const float4*)(Wr + (size_t)e * D);
      float acc = 0.f;
      #pragma unroll
      for (int j = 0; j < 3; ++j) {
        float4 w = wr4[lane + j * 64], mm = m4[lane + j * 64];
        acc = fmaf(w.x, mm.x, acc); acc = fmaf(w.y, mm.y, acc);
        acc = fmaf(w.z, mm.z, acc); acc = fmaf(w.w, mm.w, acc);
      }
      #pragma unroll
      for (int off = 32; off > 0; off >>= 1) acc += __shfl_down(acc, off);
      if (lane == 0) sp[e] = acc;
    }
    __syncthreads();
    if (t < 64) {
      float mx = -1e30f;
      for (int e = t; e < E; e += 64) mx = fmaxf(mx, sp[e]);
      #pragma unroll
      for (int off = 32; off > 0; off >>= 1) mx = fmaxf(mx, __shfl_down(mx, off));
      if (t == 0) smax = mx;
    }
    __syncthreads();
    if (t < E) sp[t] = exp2f((sp[t] - smax) * 1.44269504f);
    __syncthreads();
    if (t < 64) {
      float s = 0.f;
      for (int e = t; e < E; e += 64) s += sp[e];
      #pragma unroll
      for (int off = 32; off > 0; off >>= 1) s += __shfl_down(s, off);
      if (t == 0) ssum = s;
    }
    __syncthreads();
    if (t < E) {
      sp[t] = sp[t] / ssum;
      probs[(size_t)b * E + t] = sp[t];
    }
    __syncthreads();
    for (int k = 0; k < TK; ++k) {
      if (t < 64) {
        float bv = -1e30f; int bi = 0;
        for (int e = t; e < E; e += 64) {
          float v = sp[e];
          if (v > bv) { bv = v; bi = e; }
        }
        #pragma unroll
        for (int off = 32; off > 0; off >>= 1) {
          float ov = __shfl_down(bv, off);
          int   oi = __shfl_down(bi, off);
          if (ov > bv || (ov == bv && oi < bi)) { bv = ov; bi = oi; }
        }
        if (t == 0) {
          svals[k] = bv; sidx[k] = bi;
          sp[bi] = -2e30f;
        }
      }
      __syncthreads();
    }
    if (t == 0) {
      float s = 0.f;
      for (int k = 0; k < TK; ++k) s += svals[k];
      float inv = 1.0f / s;
      for (int k = 0; k < TK; ++k) {
        wg[b * TK + k]   = svals[k] * inv;
        idxg[b * TK + k] = sidx[k];
      }
    }
    return;
  }

  if (bx >= 800) {
    int i = (bx - 800) * 256 + t;
    float4 v = *(const float4*)&Wo[(size_t)i * 4];
    bf16x4 o = {(__bf16)v.x, (__bf16)v.y, (__bf16)v.z, (__bf16)v.w};
    *(bf16x4*)&Wob[(size_t)i * 4] = o;
    return;
  }

  // ---- W1/W2 convert, half-block: cols [r0, r0+112) ----
  int e = bx >> 2, mat = (bx >> 1) & 1, half = bx & 1;
  int r0 = half * 112;
  int nrows = half ? 84 : 112;        // real rows in this half (196 total)
  for (int i = t; i < 1792; i += 256) ((uint4*)ls)[i] = (uint4){0, 0, 0, 0};
  __syncthreads();
  const float* src = (mat ? W2 : W1) + (size_t)e * 196 * 196;
  for (int i = t; i < nrows * 49; i += 256) {
    int rl = i / 49, c4 = (i - rl * 49) * 4;
    float4 v = *(const float4*)&src[(size_t)(r0 + rl) * 196 + c4];
    int lo = __builtin_amdgcn_cvt_pk_fp8_f32(v.x, v.y, 0, false);
    unsigned int pk = (unsigned int)__builtin_amdgcn_cvt_pk_fp8_f32(v.z, v.w, lo, true);
    *(unsigned int*)&ls[rl * 256 + c4] = pk;
  }
  __syncthreads();
  uchar* dst = Wf + (size_t)e * EXB + mat * 4 * PRB;
  for (int s = t; s < 1792; s += 256) {
    int p = s / 448, rem = s - p * 448;
    int cl = rem >> 2, qp = rem & 3;
    int col = r0 + cl;
    int ql = qp ^ ((col >> 1) & 3);
    unsigned long lo = *(const unsigned long*)&ls[cl * 256 + p * 64 + ql * 8];
    unsigned long hi = *(const unsigned long*)&ls[cl * 256 + p * 64 + 32 + ql * 8];
    longx2 o; o[0] = (long)lo; o[1] = (long)hi;
    *(longx2*)&dst[(size_t)(p * 896 + col * 4 + qp) * 16] = o;
  }
}

// ---------------------------------------------------------------------------
// Kernel 5: fused expert MLP, fp8 MFMA.
// 256 thr (4 waves, 2x2 tiling), 64-row d-tile, 2 blocks/CU (79.7KB LDS).
// 4-deep prefetch ring (buffer 3 aliases zs, dead after zf hoist) ->
// ONE barrier per period.  GEMM1 swapped operands: C[h][d].
// Period 3 of both GEMMs runs HALF-K (odd 8B = k 224..255 all-zero), with
// b128 loads (KEEP64 prevents narrowing -> conflict-free bank pattern).
// ---------------------------------------------------------------------------
__global__ __launch_bounds__(256, 2) void k_expert(
    const uchar* __restrict__ zb, const uchar* __restrict__ Wf,
    const float* __restrict__ b1, const float* __restrict__ b2,
    const int* __restrict__ idxg, const float* __restrict__ wg,
    __bf16* __restrict__ mixg) {
  __shared__ alignas(16) uchar pool[75776];
  __shared__ alignas(16) __bf16 b1s[5 * 196];
  __shared__ float bsum_s[196];
  __shared__ int   eidx_s[5];
  __shared__ float w_s[5];
  uchar* zs  = pool;                 // 16384: [pair][row 0..63][64B]; ring buf 3 after hoist
  uchar* at  = pool + 16384;         // 16384: same layout (k = h)
  uchar* wsb = pool + 32768;         // 43008: ring buffers 0..2 x 14336
  __bf16* tb = (__bf16*)pool;        // final transpose scratch (after last BAR)

  int xw = blockIdx.x & 7, rr_ = blockIdx.x >> 3;
  int j = rr_ / 12, dt = rr_ - j * 12;
  int gid = j * 8 + xw;
  int g = gid & 3, b = gid >> 2;
  int d0 = dt * 64;

  int t = threadIdx.x;
  int lane = t & 63, wave = t >> 6;
  int quad = lane >> 4, l16 = lane & 15;
  int wrow = (wave & 1) * 32;        // d rows: 0 / 32
  int wcol = (wave >> 1) * 112;      // h cols: 0 / 112
  int qp = quad ^ ((l16 >> 1) & 3);  // phase-balanced XOR swizzle

  // ---- prologue ----
  if (t < 5) {
    eidx_s[t] = idxg[b * TK + g * 5 + t];
    w_s[t]    = wg[b * TK + g * 5 + t];
  }
  for (int i = t; i < 980; i += 256) {
    int kk = i / 196, col = i - kk * 196;
    int ee = idxg[b * TK + g * 5 + kk];
    b1s[i] = (__bf16)b1[ee * 196 + col];
  }
  if (t < 196) {
    float s = 0.f;
    #pragma unroll
    for (int k5 = 0; k5 < 5; ++k5) {
      int ee = idxg[b * TK + g * 5 + k5];
      s += wg[b * TK + g * 5 + k5] * b2[ee * 196 + t];
    }
    bsum_s[t] = s;
  }
  __syncthreads();   // drains prologue vmem

  // ---- z staging: 4 flat 4096-B pair blocks ----
  {
    const uchar* zbase = zb + ((size_t)b * 4 * 768 + d0) * 64;
    #pragma unroll
    for (int p = 0; p < 4; ++p)
      GLDS16(zbase + (size_t)p * (768 * 64) + t * 16, zs + p * 4096 + t * 16);
  }

  // ---- W ring staging offsets (896 slots; threads duplicate last 128) ----
  int s0 = t * 16, s1 = (t + 256) * 16, s2 = (t + 512) * 16;
  int s3 = ((t & 127) + 768) * 16;

  auto issue = [&](int qn) {
    int qq = qn > 39 ? 39 : qn;
    int kk2 = qq >> 3, rem = qq & 7;
    const uchar* src = Wf + (size_t)eidx_s[kk2] * EXB + rem * PRB;
    int bi = qn & 3;
    uchar* lb = (bi == 3) ? pool : wsb + bi * PRB;
    GLDS16(src + s0, lb + s0);
    GLDS16(src + s1, lb + s1);
    GLDS16(src + s2, lb + s2);
    GLDS16(src + s3, lb + s3);
  };
  issue(0); issue(1); issue(2);

  // ---- hoist z frags (shared across all 5 experts; B-operand of GEMM1) ----
  WAITVM12;  // z staging (oldest 4 vmem) done; ring still in flight
  BAR;
  const uchar* zbase_l = zs + (wrow + l16) * 64 + qp * 16;
  longx2 zf[3][2];
  #pragma unroll
  for (int p = 0; p < 3; ++p) {
    zf[p][0] = *(const longx2*)(zbase_l + p * 4096);
    zf[p][1] = *(const longx2*)(zbase_l + p * 4096 + 1024);
  }
  long z3r0, z3r1;
  {
    longx2 zt0 = *(const longx2*)(zbase_l + 3 * 4096);
    longx2 zt1 = *(const longx2*)(zbase_l + 3 * 4096 + 1024);
    KEEP64(zt0[1]); KEEP64(zt1[1]);
    z3r0 = zt0[0]; z3r1 = zt1[0];
  }

  const uchar* abase = at + (wrow + l16) * 64 + qp * 16;

  f32x4 macc[14];
  #pragma unroll
  for (int i = 0; i < 14; ++i) macc[i] = (f32x4){0.f, 0.f, 0.f, 0.f};

  #pragma unroll 1
  for (int kk = 0; kk < 5; ++kk) {
    float wkv = w_s[kk];
    f32x4 hacc[14];
    #pragma unroll
    for (int i = 0; i < 14; ++i) hacc[i] = (f32x4){0.f, 0.f, 0.f, 0.f};

    // ---- GEMM1: 3 full periods + 1 half-K period.  C[h][d] ----
    #pragma unroll 1
    for (int p = 0; p < 3; ++p) {
      int q = kk * 8 + p;
      WAITVM8;
      BAR;
      int bi = q & 3;
      const uchar* buf = (bi == 3) ? pool : wsb + bi * PRB;
      const uchar* bb = buf + (wcol + l16) * 64 + qp * 16;
      __builtin_amdgcn_s_setprio(1);
      #pragma unroll
      for (int ct = 0; ct < 7; ++ct) {
        longx2 bf = *(const longx2*)(bb + ct * 1024);
        hacc[ct]     = __builtin_amdgcn_mfma_f32_16x16x32_fp8_fp8(bf[0], zf[p][0][0], hacc[ct], 0, 0, 0);
        hacc[ct]     = __builtin_amdgcn_mfma_f32_16x16x32_fp8_fp8(bf[1], zf[p][0][1], hacc[ct], 0, 0, 0);
        hacc[7 + ct] = __builtin_amdgcn_mfma_f32_16x16x32_fp8_fp8(bf[0], zf[p][1][0], hacc[7 + ct], 0, 0, 0);
        hacc[7 + ct] = __builtin_amdgcn_mfma_f32_16x16x32_fp8_fp8(bf[1], zf[p][1][1], hacc[7 + ct], 0, 0, 0);
      }
      __builtin_amdgcn_s_setprio(0);
      issue(q + 3);
    }
    {
      int q = kk * 8 + 3;           // half-K: tokens 192..223 only
      WAITVM8;
      BAR;
      int bi = q & 3;
      const uchar* buf = (bi == 3) ? pool : wsb + bi * PRB;
      const uchar* bb = buf + (wcol + l16) * 64 + qp * 16;
      __builtin_amdgcn_s_setprio(1);
      #pragma unroll
      for (int ct = 0; ct < 7; ++ct) {
        longx2 bf = *(const longx2*)(bb + ct * 1024);
        KEEP64(bf[1]);              // force b128 read (bank-friendly)
        hacc[ct]     = __builtin_amdgcn_mfma_f32_16x16x32_fp8_fp8(bf[0], z3r0, hacc[ct], 0, 0, 0);
        hacc[7 + ct] = __builtin_amdgcn_mfma_f32_16x16x32_fp8_fp8(bf[0], z3r1, hacc[7 + ct], 0, 0, 0);
      }
      __builtin_amdgcn_s_setprio(0);
      issue(q + 3);
    }

    // ---- epilogue: a = gelu(h+b1)*w_k -> at, packed 4 h per b32 store ----
    // lane holds h = wcol + ct*16 + quad*4 + (0..3) at d = wrow + rt*16 + l16.
    // at byte addr: (h>>6)*4096 + d*64 + ((((h>>3)&3) ^ ((d>>1)&3))<<4)
    //             + ((h>>5)&1)*8 + (h&7)   -- matches GEMM2's reads.
    // invalid hb (196..220) stores 0, zeroing pair-3 even-half tail each kk.
    #pragma unroll
    for (int ct = 0; ct < 7; ++ct) {
      int hb = wcol + ct * 16 + quad * 4;
      bool valid = hb < 196;
      unsigned pk0 = 0u, pk1 = 0u;
      if (valid) {
        bf16x4 b4 = *(const bf16x4*)&b1s[kk * 196 + hb];
        float bv0 = (float)b4[0], bv1 = (float)b4[1];
        float bv2 = (float)b4[2], bv3 = (float)b4[3];
        f32x4 h0 = hacc[ct], h1 = hacc[7 + ct];
        pk0 = (unsigned)__builtin_amdgcn_cvt_pk_fp8_f32(
                  gelu_fast(h0[0] + bv0) * wkv, gelu_fast(h0[1] + bv1) * wkv, 0, false);
        pk0 = (unsigned)__builtin_amdgcn_cvt_pk_fp8_f32(
                  gelu_fast(h0[2] + bv2) * wkv, gelu_fast(h0[3] + bv3) * wkv, (int)pk0, true);
        pk1 = (unsigned)__builtin_amdgcn_cvt_pk_fp8_f32(
                  gelu_fast(h1[0] + bv0) * wkv, gelu_fast(h1[1] + bv1) * wkv, 0, false);
        pk1 = (unsigned)__builtin_amdgcn_cvt_pk_fp8_f32(
                  gelu_fast(h1[2] + bv2) * wkv, gelu_fast(h1[3] + bv3) * wkv, (int)pk1, true);
      }
      int d0r = wrow + l16;
      int addr0 = (hb >> 6) * 4096 + d0r * 64 + ((((hb >> 3) & 3) ^ ((d0r >> 1) & 3)) << 4)
                + ((hb >> 5) & 1) * 8 + (quad & 1) * 4;
      *(unsigned*)&at[addr0]        = pk0;   // rt = 0: d = wrow + l16
      *(unsigned*)&at[addr0 + 1024] = pk1;   // rt = 1: d+16, same chunk-xor
    }
    WAITLGKM0;   // own at-writes drained before the next barrier

    // ---- GEMM2: 3 full periods + 1 half-K period (C[d][n]) ----
    #pragma unroll 1
    for (int p = 0; p < 3; ++p) {
      int q = kk * 8 + 4 + p;
      WAITVM8;
      BAR;
      int bi = q & 3;
      const uchar* buf = (bi == 3) ? pool : wsb + bi * PRB;
      const uchar* bb = buf + (wcol + l16) * 64 + qp * 16;
      longx2 a0 = *(const longx2*)(abase + p * 4096);
      longx2 a1 = *(const longx2*)(abase + p * 4096 + 1024);
      __builtin_amdgcn_s_setprio(1);
      #pragma unroll
      for (int ct = 0; ct < 7; ++ct) {
        longx2 bf = *(const longx2*)(bb + ct * 1024);
        macc[ct]     = __builtin_amdgcn_mfma_f32_16x16x32_fp8_fp8(a0[0], bf[0], macc[ct], 0, 0, 0);
        macc[ct]     = __builtin_amdgcn_mfma_f32_16x16x32_fp8_fp8(a0[1], bf[1], macc[ct], 0, 0, 0);
        macc[7 + ct] = __builtin_amdgcn_mfma_f32_16x16x32_fp8_fp8(a1[0], bf[0], macc[7 + ct], 0, 0, 0);
        macc[7 + ct] = __builtin_amdgcn_mfma_f32_16x16x32_fp8_fp8(a1[1], bf[1], macc[7 + ct], 0, 0, 0);
      }
      __builtin_amdgcn_s_setprio(0);
      issue(q + 3);
    }
    {
      int q = kk * 8 + 7;           // half-K: h 192..223 only
      WAITVM8;
      BAR;
      int bi = q & 3;
      const uchar* buf = (bi == 3) ? pool : wsb + bi * PRB;
      const uchar* bb = buf + (wcol + l16) * 64 + qp * 16;
      long a0h, a1h;
      {
        longx2 at0 = *(const longx2*)(abase + 3 * 4096);
        longx2 at1 = *(const longx2*)(abase + 3 * 4096 + 1024);
        KEEP64(at0[1]); KEEP64(at1[1]);
        a0h = at0[0]; a1h = at1[0];
      }
      __builtin_amdgcn_s_setprio(1);
      #pragma unroll
      for (int ct = 0; ct < 7; ++ct) {
        longx2 bf = *(const longx2*)(bb + ct * 1024);
        KEEP64(bf[1]);              // force b128 read (bank-friendly)
        macc[ct]     = __builtin_amdgcn_mfma_f32_16x16x32_fp8_fp8(a0h, bf[0], macc[ct], 0, 0, 0);
        macc[7 + ct] = __builtin_amdgcn_mfma_f32_16x16x32_fp8_fp8(a1h, bf[0], macc[7 + ct], 0, 0, 0);
      }
      __builtin_amdgcn_s_setprio(0);
      issue(q + 3);
    }
  }

  // ---- drain async; add bsum = sum_k w_k*b2_k[n]; packed b64 transpose ----
  WAITVM0;
  BAR;
  #pragma unroll
  for (int ct = 0; ct < 7; ++ct) {
    int ncol = wcol + ct * 16 + l16;
    float bsum = (ncol < 196) ? bsum_s[ncol] : 0.f;
    #pragma unroll
    for (int rt = 0; rt < 2; ++rt) {
      f32x4 v = macc[rt * 7 + ct];
      bf16x4 o = {(__bf16)(v[0] + bsum), (__bf16)(v[1] + bsum),
                  (__bf16)(v[2] + bsum), (__bf16)(v[3] + bsum)};
      *(bf16x4*)&tb[ncol * 68 + wrow + rt * 16 + quad * 4] = o;
    }
  }
  __syncthreads();
  __bf16* mp = mixg + ((size_t)(g * B + b) * N) * D + d0;
  #pragma unroll
  for (int i = 0; i < 7; ++i) {
    int s = i * 256 + t;
    if (s < 1568) {
      int n = s >> 3, c = s & 7;
      const uint2* pa = (const uint2*)&tb[n * 68 + c * 8];
      uint2 v0 = pa[0], v1 = pa[1];
      uint4 v = {v0.x, v0.y, v1.x, v1.y};
      *(uint4*)&mp[(size_t)n * D + c * 8] = v;
    }
  }
}

// ---------------------------------------------------------------------------
// Kernel 6: out = (sum_g mixg_g) @ Wo^T + bo; block 0 also computes aux loss.
// 32-row m-tiles (grid 588), K-step 64 (12 iters, half the barriers),
// 3 blocks/CU -> all 588 blocks resident.
// ---------------------------------------------------------------------------
__global__ __launch_bounds__(256, 3) void k_outproj(
    const __bf16* __restrict__ mixg, const __bf16* __restrict__ Wob,
    const float* __restrict__ bo, const float* __restrict__ probs,
    const int* __restrict__ idxg, float* __restrict__ out,
    float* __restrict__ out_aux) {
  __shared__ alignas(16) __bf16 As[32 * LK2];    // 4608 B
  __shared__ alignas(16) __bf16 Bs[256 * LK2];   // 36864 B
  const size_t GS = (size_t)B * N * D;

  int t = threadIdx.x;
  if (blockIdx.x == 0 && t < 32) {
    int top1 = idxg[t * TK];
    float s = 0.f;
    for (int bb = 0; bb < B; ++bb) s += probs[(size_t)bb * E + top1];
    #pragma unroll
    for (int off = 16; off > 0; off >>= 1) s += __shfl_down(s, off);
    if (t == 0) out_aux[0] = s * ((float)E / ((float)B * (float)B));
  }

  int m0 = (blockIdx.x % 196) * 32;
  int e0 = (blockIdx.x / 196) * 256;
  int lane = t & 63, wave = t >> 6;
  int quad = lane >> 4, l16 = lane & 15;
  int wrow = (wave & 1) * 16;
  int wcol = (wave >> 1) * 128;
  int arow = t >> 3, ach = t & 7;      // A-staging: all 256 threads, 32 rows x 64 k
  const __bf16* ap0 = mixg + (size_t)(m0 + arow) * D + ach * 8;

  f32x4 acc[8];
  #pragma unroll
  for (int i = 0; i < 8; ++i) acc[i] = (f32x4){0.f, 0.f, 0.f, 0.f};

  const uint4* wsrc = (const uint4*)Wob;
  #pragma unroll 1
  for (int c = 0; c < 12; ++c) {
    int k0 = c * 64;
    __syncthreads();
    {
      const __bf16* ap = ap0 + k0;
      bf16x8 g0 = *(const bf16x8*)(ap);
      bf16x8 g1 = *(const bf16x8*)(ap + GS);
      bf16x8 g2 = *(const bf16x8*)(ap + 2 * GS);
      bf16x8 g3 = *(const bf16x8*)(ap + 3 * GS);
      bf16x8 r;
      #pragma unroll
      for (int jj = 0; jj < 8; ++jj)
        r[jj] = (__bf16)((float)g0[jj] + (float)g1[jj] + (float)g2[jj] + (float)g3[jj]);
      *(bf16x8*)&As[arow * LK2 + ach * 8] = r;
    }
    #pragma unroll
    for (int i = 0; i < 8; ++i) {
      int p = i * 256 + t;
      int rr = p >> 3, sub = p & 7;
      uint4 v = wsrc[(((size_t)(e0 + rr)) * D + k0) / 8 + sub];
      *(uint4*)&Bs[rr * LK2 + sub * 8] = v;
    }
    __syncthreads();
    bf16x8 a0 = *(const bf16x8*)&As[(wrow + l16) * LK2 + quad * 8];
    bf16x8 a1 = *(const bf16x8*)&As[(wrow + l16) * LK2 + 32 + quad * 8];
    #pragma unroll
    for (int ct = 0; ct < 8; ++ct) {
      const __bf16* brow = &Bs[(wcol + ct * 16 + l16) * LK2];
      bf16x8 b0 = *(const bf16x8*)(brow + quad * 8);
      bf16x8 b1 = *(const bf16x8*)(brow + 32 + quad * 8);
      acc[ct] = __builtin_amdgcn_mfma_f32_16x16x32_bf16(a0, b0, acc[ct], 0, 0, 0);
      acc[ct] = __builtin_amdgcn_mfma_f32_16x16x32_bf16(a1, b1, acc[ct], 0, 0, 0);
    }
  }

  #pragma unroll
  for (int ct = 0; ct < 8; ++ct) {
    int e = e0 + wcol + ct * 16 + l16;
    float bov = bo[e];
    #pragma unroll
    for (int rx = 0; rx < 4; ++rx) {
      int m = m0 + wrow + quad * 4 + rx;
      out[(size_t)m * D + e] = acc[ct][rx] + bov;
    }
  }
}

// ---------------------------------------------------------------------------
extern "C" void kernel_launch(void* const* d_in, const int* in_sizes, int n_in,
                              void* d_out, int out_size, void* d_ws, size_t ws_size,
                              hipStream_t stream) {
  const float* x  = (const float*)d_in[0];
  const float* Wr = (const float*)d_in[1];
  const float* W1 = (const float*)d_in[2];
  const float* b1 = (const float*)d_in[3];
  const float* W2 = (const float*)d_in[4];
  const float* b2 = (const float*)d_in[5];
  const float* Wo = (const float*)d_in[6];
  const float* bo = (const float*)d_in[7];
  float* out = (float*)d_out;

  char* p = (char*)d_ws;
  auto alloc = [&](size_t bytes) {
    char* r = p;
    p += (bytes + 255) & ~(size_t)255;
    return r;
  };
  uchar*  zb   = (uchar*)alloc((size_t)B * 4 * 768 * 64);
  float*  mu   = (float*)alloc((size_t)B * D * 4);
  uchar*  Wf   = (uchar*)alloc((size_t)E * EXB);
  __bf16* Wob  = (__bf16*)alloc((size_t)D * D * 2);
  __bf16* mixg = (__bf16*)alloc((size_t)NGRP * B * N * D * 2);
  float*  probs= (float*)alloc((size_t)B * E * 4);
  int*    idxg = (int*)alloc((size_t)B * TK * 4);
  float*  wg   = (float*)alloc((size_t)B * TK * 4);

  k_ln<<<dim3(B * 12), dim3(256), 0, stream>>>(x, zb, mu);
  k_prep<<<dim3(1408), dim3(256), 0, stream>>>(W1, W2, Wo, Wf, Wob,
                                               mu, Wr, probs, idxg, wg);
  k_expert<<<dim3(1536), dim3(256), 0, stream>>>(zb, Wf, b1, b2, idxg, wg, mixg);
  k_outproj<<<dim3(588), dim3(256), 0, stream>>>(mixg, Wob, bo, probs, idxg,
                                                 out, out + (size_t)B * N * D);
}